// Round 11
// baseline (57.374 us; speedup 1.0000x reference)
//
#include <hip/hip_runtime.h>
#include <hip/hip_bf16.h>

// Causal conv1d as bf16 MFMA GEMM — 128x128 tile, 32x32x16 MFMA, A staged
// 2 steps ahead (counted vmcnt never drains same-step loads), uniform issue.
// out[b,h,t] = sum_{c,k} x[b,c,t+k-3] * W[h, c*4+k] + bias[h]
// B=8, C=256, T=4096, H=512, K=4.

#define Bb 8
#define Cc 256
#define Tt 4096
#define Hh 512
#define Kk 4

typedef __attribute__((ext_vector_type(8)))  short bf16x8;
typedef __attribute__((ext_vector_type(16))) float f32x16;

#define WS_XT_OFF   0
#define WS_WT_OFF   16777216
#define WS_ZERO_OFF 17825792
#define WS_NEEDED   17826816ULL

__device__ __forceinline__ void gload16(const void* g, void* l) {
    __builtin_amdgcn_global_load_lds(
        (const __attribute__((address_space(1))) void*)g,
        (__attribute__((address_space(3))) void*)l, 16, 0, 0);
}

// ---------- merged prep: xT transpose (blocks 0..2047) + Wt[k][h][c] pack ----------
__global__ __launch_bounds__(256) void prep_kernel(const float* __restrict__ x,
                                                   const float* __restrict__ W,
                                                   __hip_bfloat16* __restrict__ xT,
                                                   __hip_bfloat16* __restrict__ Wt,
                                                   float* __restrict__ zeros) {
    __shared__ __hip_bfloat16 tile[64][72];
    const int bid = blockIdx.x;
    if (bid < 2048) {
        const int t0 = (bid & 63) * 64, c0 = ((bid >> 6) & 3) * 64, b = bid >> 8;
        const int lt = threadIdx.x & 63, lw = threadIdx.x >> 6;
#pragma unroll
        for (int i = 0; i < 16; ++i) {
            int cc = lw + i * 4;
            tile[cc][lt] = __float2bfloat16(x[((size_t)(b * Cc + c0 + cc)) * Tt + t0 + lt]);
        }
        __syncthreads();
#pragma unroll
        for (int i = 0; i < 2; ++i) {
            int tt = (threadIdx.x >> 3) + i * 32;
            int c8 = threadIdx.x & 7;
            short tmp[8];
#pragma unroll
            for (int j = 0; j < 8; ++j) {
                __hip_bfloat16 v = tile[c8 * 8 + j][tt];
                tmp[j] = *reinterpret_cast<short*>(&v);
            }
            *reinterpret_cast<bf16x8*>(&xT[((size_t)(b * Tt + t0 + tt)) * Cc + c0 + c8 * 8]) =
                *reinterpret_cast<bf16x8*>(tmp);
        }
    } else {
        int n = (bid - 2048) * 256 + threadIdx.x;     // [0, 4*512*256)
        int c = n & 255;
        int h = (n >> 8) & 511;
        int k = n >> 17;
        Wt[n] = __float2bfloat16(W[h * (Cc * Kk) + c * Kk + k]);
        if (bid == 2048) zeros[threadIdx.x] = 0.f;    // 1 KB zero page
    }
}

// ---------- main: BM=128h x BN=128t, 4 waves (2x2 -> 64x64/wave), 32x32x16 ----------
// 16 K-steps of GEMM-K 64 = 2 conv-k x 32 ch (kpair = s&1, cblk = s>>1).
// LDS: A 3 bufs x [2kk][128 rows][4 slots x 16B] = 3x16384 (staged 2 steps ahead);
//      B 2 bufs x [144 rows][4 slots x 16B] = 2x9216.  Total 67584 -> 2 blocks/CU.
// Swizzle (r6/r10-validated): slot_phys = slot_log ^ ((row>>1)&3), folded into src.
#define A_BUF    16384
#define B_BUF    9216
#define B_BASE   49152
#define LDS_TOTAL 67584

#define BAR __builtin_amdgcn_s_barrier()
#define LGKM0 do { asm volatile("s_waitcnt lgkmcnt(0)" ::: "memory"); \
                   __builtin_amdgcn_sched_barrier(0); } while (0)

__global__ __launch_bounds__(256, 2) void conv_mfma_kernel(
    const __hip_bfloat16* __restrict__ xT,
    const __hip_bfloat16* __restrict__ Wt,
    const float* __restrict__ bias,
    const float* __restrict__ zeros,
    float* __restrict__ out)
{
    __shared__ __align__(1024) char smem[LDS_TOTAL];
    const int tid = threadIdx.x, lane = tid & 63, wave = tid >> 6;
    const int wr = wave >> 1, wc = wave & 1;          // 2(M h) x 2(N t)
    const int l31 = lane & 31, lh = lane >> 5;

    // XCD-bijective swizzle (r10): batch <-> XCD; 4 h-tiles share each t-window.
    const int flat = blockIdx.x + 32 * blockIdx.y + 128 * blockIdx.z;
    const int nf   = (flat & 7) * 128 + (flat >> 3);
    const int h0 = (nf & 3) * 128;
    const int t0 = ((nf >> 2) & 31) * 128;
    const int b  = nf >> 7;

    const char* Wt_c = (const char*)Wt;
    const char* xT_c = (const char*)xT;
    const char* zz   = (const char*)zeros;

    // ---- A staging descriptors (linear LDS dst; swizzle folded into global src) ----
    const char* asrc[4]; int adst_[4];
#pragma unroll
    for (int i = 0; i < 4; ++i) {
        int s = tid + i * 256;                        // 0..1023
        int kk = s >> 9, row = (s >> 2) & 127, sl = s & 3;
        int colch = (sl ^ ((row >> 1) & 3)) * 8;
        asrc[i] = Wt_c + (((size_t)(kk * Hh + h0 + row)) * Cc + colch) * 2;
        adst_[i] = s * 16;
    }
    // ---- B staging descriptors; ALL waves load the tail (uniform vmcnt counts) ----
    const char* bsrc[3]; int bdst_[3]; int bstep[3];
#pragma unroll
    for (int i = 0; i < 3; ++i) {
        int s = (i < 2) ? tid + i * 256 : 512 + lane; // rows 0..143
        int row = s >> 2, sl = s & 3;
        int colch = (sl ^ ((row >> 1) & 3)) * 8;
        int tg = t0 - 3 + row;
        bool valid = (row <= 130) && (tg >= 0);
        bsrc[i]  = valid ? xT_c + (((size_t)b * Tt + tg) * Cc + colch) * 2
                         : zz + (s & 15) * 16;
        bstep[i] = valid ? 64 : 0;                    // +64B per c-block; zeros stay put
        bdst_[i] = s * 16;
    }

    // ---- fragment read bases (32x32 frag: row = base + l31, kgroup = lh) ----
    int arow[2], aswz[2];
#pragma unroll
    for (int fm = 0; fm < 2; ++fm) {
        int r = wr * 64 + fm * 32 + l31;
        arow[fm] = r * 64; aswz[fm] = (r >> 1) & 3;
    }
    int brow[4][2], bswz[4][2];
#pragma unroll
    for (int ck = 0; ck < 4; ++ck)
#pragma unroll
        for (int ft = 0; ft < 2; ++ft) {
            int r = wc * 64 + ft * 32 + l31 + ck;     // conv-k row shift
            brow[ck][ft] = r * 64; bswz[ck][ft] = (r >> 1) & 3;
        }

    f32x16 acc[2][2] = {};

    int A0 = 0, A1 = A_BUF, A2 = 2 * A_BUF;
    int Bc = B_BASE, Bn = B_BASE + B_BUF;

    // ---- prologue: A(0), B(0), A(1); vmcnt(4) -> A(0),B(0) landed, A(1) in flight ----
#pragma unroll
    for (int i = 0; i < 4; ++i) gload16(asrc[i], smem + A0 + adst_[i]);
#pragma unroll
    for (int i = 0; i < 3; ++i) gload16(bsrc[i], smem + Bc + bdst_[i]);
#pragma unroll
    for (int i = 0; i < 4; ++i) gload16(asrc[i] + 524288, smem + A1 + adst_[i]);
    asm volatile("s_waitcnt vmcnt(4)" ::: "memory");
    BAR;

    // ---- main loop: 16 steps; stage A(s+2)/B(p+1); 16 MFMA/step ----
#pragma unroll 2
    for (int s = 0; s < 16; ++s) {
        const int kb = (s & 1) * 2;

        if (s <= 13) {                                // stage A(s+2) into A2
            const long aadv = (long)((s + 2) & 1) * 524288 + (long)((s + 2) >> 1) * 64;
#pragma unroll
            for (int i = 0; i < 4; ++i) gload16(asrc[i] + aadv, smem + A2 + adst_[i]);
        }
        if (((s & 1) == 0) && (s <= 12)) {            // stage B(p+1) into Bn
            const int bu = (s >> 1) + 1;
#pragma unroll
            for (int i = 0; i < 3; ++i) gload16(bsrc[i] + bu * bstep[i], smem + Bn + bdst_[i]);
        }

#pragma unroll
        for (int kk = 0; kk < 2; ++kk) {
            const int ck = kb + kk;
            bf16x8 a_[2][2], b_[2][2];                // [sub16][fm/ft]
#pragma unroll
            for (int sub = 0; sub < 2; ++sub) {
#pragma unroll
                for (int fm = 0; fm < 2; ++fm)
                    a_[sub][fm] = *(const bf16x8*)(smem + A0 + kk * 8192 + arow[fm]
                                    + (((sub * 2 + lh) ^ aswz[fm]) << 4));
#pragma unroll
                for (int ft = 0; ft < 2; ++ft)
                    b_[sub][ft] = *(const bf16x8*)(smem + Bc + brow[ck][ft]
                                    + (((sub * 2 + lh) ^ bswz[ck][ft]) << 4));
            }
            LGKM0;
            __builtin_amdgcn_s_setprio(1);
#pragma unroll
            for (int sub = 0; sub < 2; ++sub)
#pragma unroll
                for (int fm = 0; fm < 2; ++fm)
#pragma unroll
                    for (int ft = 0; ft < 2; ++ft)
                        acc[fm][ft] = __builtin_amdgcn_mfma_f32_32x32x16_bf16(
                            a_[sub][fm], b_[sub][ft], acc[fm][ft], 0, 0, 0);
            __builtin_amdgcn_s_setprio(0);
        }

        if (s < 15) {
            // counted waits: drain A(s+1) (+B(p+1) at odd); never same-step loads
            if (s & 1)          asm volatile("s_waitcnt vmcnt(4)" ::: "memory");
            else if (s <= 12)   asm volatile("s_waitcnt vmcnt(7)" ::: "memory");
            else                asm volatile("s_waitcnt vmcnt(0)" ::: "memory");  // s==14
            BAR;
        }
        int t_ = A0; A0 = A1; A1 = A2; A2 = t_;       // rotate A bufs
        if (s & 1) { int u_ = Bc; Bc = Bn; Bn = u_; } // swap B bufs per pair
    }

    // ---- epilogue: 32x32 D layout (r4-validated): col=l31->t, row hl->h ----
#pragma unroll
    for (int fm = 0; fm < 2; ++fm)
#pragma unroll
        for (int ft = 0; ft < 2; ++ft)
#pragma unroll
            for (int r = 0; r < 16; ++r) {
                int hl = (r & 3) + 8 * (r >> 2) + 4 * lh;
                int h  = h0 + wr * 64 + fm * 32 + hl;
                int t  = t0 + wc * 64 + ft * 32 + l31;
                out[((size_t)(b * Hh + h)) * Tt + t] = acc[fm][ft][r] + bias[h];
            }
}

// ---------------- fallback (ws too small): fp32 kernel ----------------
#define TT 256
#define HT 8
#define CT 4
__global__ __launch_bounds__(256) void conv1d_f32_kernel(
    const float* __restrict__ x, const float* __restrict__ W,
    const float* __restrict__ bias, float* __restrict__ out)
{
    const int tid = threadIdx.x;
    const int t0 = blockIdx.x * TT;
    const int h0 = blockIdx.y * HT;
    const int b  = blockIdx.z;
    __shared__ float xs[CT][TT + Kk];
    float acc[HT];
#pragma unroll
    for (int h = 0; h < HT; ++h) acc[h] = 0.f;
    const float* xb = x + (size_t)b * Cc * Tt;
    for (int c0 = 0; c0 < Cc; c0 += CT) {
        __syncthreads();
#pragma unroll
        for (int cc = 0; cc < CT; ++cc)
            for (int j = tid; j < TT + Kk - 1; j += 256) {
                int idx = t0 - (Kk - 1) + j;
                xs[cc][j] = (idx >= 0) ? xb[(size_t)(c0 + cc) * Tt + idx] : 0.f;
            }
        __syncthreads();
#pragma unroll
        for (int cc = 0; cc < CT; ++cc) {
            float xv[Kk];
#pragma unroll
            for (int k = 0; k < Kk; ++k) xv[k] = xs[cc][tid + k];
#pragma unroll
            for (int h = 0; h < HT; ++h) {
                const float* wp = W + (size_t)(h0 + h) * (Cc * Kk) + (size_t)(c0 + cc) * Kk;
#pragma unroll
                for (int k = 0; k < Kk; ++k) acc[h] += wp[k] * xv[k];
            }
        }
    }
#pragma unroll
    for (int h = 0; h < HT; ++h)
        out[((size_t)b * Hh + (h0 + h)) * Tt + t0 + tid] = acc[h] + bias[h0 + h];
}

extern "C" void kernel_launch(void* const* d_in, const int* in_sizes, int n_in,
                              void* d_out, int out_size, void* d_ws, size_t ws_size,
                              hipStream_t stream) {
    const float* x    = (const float*)d_in[0];
    const float* W    = (const float*)d_in[1];
    const float* bias = (const float*)d_in[2];
    float* out        = (float*)d_out;

    if (ws_size >= WS_NEEDED) {
        __hip_bfloat16* xT = (__hip_bfloat16*)((char*)d_ws + WS_XT_OFF);
        __hip_bfloat16* Wt = (__hip_bfloat16*)((char*)d_ws + WS_WT_OFF);
        float* zeros       = (float*)((char*)d_ws + WS_ZERO_OFF);

        prep_kernel<<<dim3(4096), dim3(256), 0, stream>>>(x, W, xT, Wt, zeros);
        conv_mfma_kernel<<<dim3(32, 4, 8), dim3(256), 0, stream>>>(xT, Wt, bias, zeros, out);
    } else {
        conv1d_f32_kernel<<<dim3(Tt / TT, Hh / HT, Bb), dim3(256), 0, stream>>>(x, W, bias, out);
    }
}

// Round 12
// 49.740 us; speedup vs baseline: 1.1535x; 1.1535x over previous
//
#include <hip/hip_runtime.h>
#include <hip/hip_bf16.h>

// Causal conv1d as bf16 MFMA GEMM — r6 shell + frag-prefetch counted-lgkm
// pipeline + linear pre-tiled Wt2 staging.  (Best measured: 49.33 us total.)
// out[b,h,t] = sum_{c,k} x[b,c,t+k-3] * W[h, c*4+k] + bias[h]
// B=8, C=256, T=4096, H=512, K=4.

#define Bb 8
#define Cc 256
#define Tt 4096
#define Hh 512
#define Kk 4

typedef __attribute__((ext_vector_type(8))) short bf16x8;
typedef __attribute__((ext_vector_type(4))) float f32x4;

#define WS_XT_OFF   0
#define WS_WT_OFF   16777216
#define WS_ZERO_OFF 17825792
#define WS_NEEDED   17826816ULL

__device__ __forceinline__ void gload16(const void* g, void* l) {
    __builtin_amdgcn_global_load_lds(
        (const __attribute__((address_space(1))) void*)g,
        (__attribute__((address_space(3))) void*)l, 16, 0, 0);
}

// ---------- merged prep: xT transpose (blocks 0..2047) + Wt2 LDS-image pack ----------
// Wt2[h0t][st][slot][e]: slot s: row=(s>>2)&255, sl=s&3, kk=s>>10;
//   h = h0t*256+row, c = (st>>1)*32 + ((sl^((row>>1)&3))<<3)+e, k = (st&1)*2+kk.
__global__ __launch_bounds__(256) void prep_kernel(const float* __restrict__ x,
                                                   const float* __restrict__ W,
                                                   __hip_bfloat16* __restrict__ xT,
                                                   __hip_bfloat16* __restrict__ Wt2,
                                                   float* __restrict__ zeros) {
    __shared__ __hip_bfloat16 tile[64][72];
    const int bid = blockIdx.x;
    if (bid < 2048) {
        const int t0 = (bid & 63) * 64, c0 = ((bid >> 6) & 3) * 64, b = bid >> 8;
        const int lt = threadIdx.x & 63, lw = threadIdx.x >> 6;
#pragma unroll
        for (int i = 0; i < 16; ++i) {
            int cc = lw + i * 4;
            tile[cc][lt] = __float2bfloat16(x[((size_t)(b * Cc + c0 + cc)) * Tt + t0 + lt]);
        }
        __syncthreads();
#pragma unroll
        for (int i = 0; i < 2; ++i) {
            int tt = (threadIdx.x >> 3) + i * 32;
            int c8 = threadIdx.x & 7;
            short tmp[8];
#pragma unroll
            for (int j = 0; j < 8; ++j) {
                __hip_bfloat16 v = tile[c8 * 8 + j][tt];
                tmp[j] = *reinterpret_cast<short*>(&v);
            }
            *reinterpret_cast<bf16x8*>(&xT[((size_t)(b * Tt + t0 + tt)) * Cc + c0 + c8 * 8]) =
                *reinterpret_cast<bf16x8*>(tmp);
        }
    } else {
        int n2 = (bid - 2048) * 256 + threadIdx.x;    // [0, 524288)
        int e   = n2 & 7;
        int s   = (n2 >> 3) & 2047;
        int st  = (n2 >> 14) & 15;
        int h0t = n2 >> 18;
        int row = (s >> 2) & 255, sl = s & 3, kk = s >> 10;
        int c = (st >> 1) * 32 + ((sl ^ ((row >> 1) & 3)) << 3) + e;
        int k = (st & 1) * 2 + kk;
        int h = h0t * 256 + row;
        Wt2[n2] = __float2bfloat16(W[h * (Cc * Kk) + c * Kk + k]);
        if (bid == 2048) zeros[threadIdx.x] = 0.f;    // 1 KB zero page
    }
}

// ---------- main: BM=256h x BN=256t, 8 waves (2Mx4N -> 128x64/wave), 16x16x32 ----------
// K-step = 2 conv-k x 32 ch (GEMM-K 64); 16 steps; 4 phases/step with
// one-phase-ahead frag prefetch (counted lgkmcnt 4/8/4/0).
#define A_STRIDE 32768
#define B_BASE   98304
#define B_STRIDE 17408
#define LDS_TOTAL 133120

#define BAR __builtin_amdgcn_s_barrier()
#define LGKM(n) do { asm volatile("s_waitcnt lgkmcnt(" #n ")" ::: "memory"); \
                     __builtin_amdgcn_sched_barrier(0); } while (0)

__global__ __launch_bounds__(512, 1) void conv_mfma_kernel(
    const __hip_bfloat16* __restrict__ xT,
    const __hip_bfloat16* __restrict__ Wt2,
    const float* __restrict__ bias,
    const float* __restrict__ zeros,
    float* __restrict__ out)
{
    __shared__ __align__(1024) char smem[LDS_TOTAL];
    const int tid = threadIdx.x, lane = tid & 63, wave = tid >> 6;
    const int wr = wave >> 2, wc = wave & 3;          // 2(M h) x 4(N t)
    const int l15 = lane & 15, lg = lane >> 4;

    // XCD swizzle: 256 blocks, XCD x gets batch x (2MB xT slice L2-resident)
    const int nf = (blockIdx.x & 7) * 32 + (blockIdx.x >> 3);
    const int t0 = (nf & 15) * 256;
    const int h0 = ((nf >> 4) & 1) * 256;
    const int b  = nf >> 5;

    const char* aW   = (const char*)Wt2 + (h0 >> 8) * 524288;  // pre-tiled LDS image
    const char* xT_c = (const char*)xT;
    const char* zz   = (const char*)zeros;

    // ---- A staging: linear (slot i*512+tid), src = aW + step*32768 + slot*16 ----
    int aslot[4];
#pragma unroll
    for (int i = 0; i < 4; ++i) aslot[i] = (tid + i * 512) * 16;

    // ---- B staging descriptors (r6-validated) ----
    const char* bsrc[2]; int bdst[2];
#pragma unroll
    for (int i = 0; i < 2; ++i) {
        int s = tid + i * 512;                        // rows 0..255
        int row = s >> 2, sl = s & 3;
        int colch = (sl ^ ((row >> 1) & 3)) * 8;
        int tg = t0 - 3 + row;
        bsrc[i] = (tg >= 0 && tg < Tt)
                ? xT_c + (((size_t)b * Tt + tg) * Cc + colch) * 2 : zz;
        bdst[i] = s * 16;
    }
    const char* btsrc; {                              // tail rows 256..258 (+pad)
        int row = 256 + (lane >> 2), sl = lane & 3;
        int colch = (sl ^ ((row >> 1) & 3)) * 8;
        int tg = t0 - 3 + row;
        btsrc = (row <= 258 && tg < Tt)
              ? xT_c + (((size_t)b * Tt + tg) * Cc + colch) * 2 : zz;
    }

    // ---- fragment read offsets (r6-validated swizzle) ----
    const int aoffb = (wr * 128 + l15) * 64 + ((lg ^ ((l15 >> 1) & 3)) << 4);
    int bofftab[4];
#pragma unroll
    for (int k = 0; k < 4; ++k)
        bofftab[k] = (wc * 64 + l15 + k) * 64 + ((lg ^ (((l15 + k) >> 1) & 3)) << 4);
    const int boff0 = bofftab[0], boff1 = bofftab[1];
    const int boff2 = bofftab[2], boff3 = bofftab[3];

    f32x4 acc[8][4] = {};

    // ---- prologue: A(0), B(0), A(1); vmcnt(4) keeps A(1) in flight ----
#pragma unroll
    for (int i = 0; i < 4; ++i) gload16(aW + aslot[i], smem + aslot[i]);
#pragma unroll
    for (int i = 0; i < 2; ++i) gload16(bsrc[i], smem + B_BASE + bdst[i]);
    gload16(btsrc, smem + B_BASE + 16384);
#pragma unroll
    for (int i = 0; i < 4; ++i) gload16(aW + 32768 + aslot[i], smem + A_STRIDE + aslot[i]);
    asm volatile("s_waitcnt vmcnt(4)" ::: "memory");
    BAR;

    // ---- main loop: 16 K-steps x 4 phases, frag prefetch 1 phase ahead ----
#pragma unroll
    for (int s = 0; s < 16; ++s) {
        const char* Ab  = smem + (s % 3) * A_STRIDE;
        const char* Bbf = smem + B_BASE + ((s >> 1) & 1) * B_STRIDE;
        char* And = smem + ((s + 2) % 3) * A_STRIDE;
        char* Bnd = smem + B_BASE + (((s >> 1) + 1) & 1) * B_STRIDE;
        const bool doA = (s + 2) <= 15;
        const bool doB = ((s & 1) == 0) && ((s >> 1) + 1 <= 7);
        const long aoffg = (long)(s + 2) * 32768;
        const int  badv  = ((s >> 1) + 1) * 64;
        const int  bo0 = (s & 1) ? boff2 : boff0;
        const int  bo1 = (s & 1) ? boff3 : boff1;

        bf16x8 fA0[4], fB0[4], fA1[4], fA2[4], fB2[4], fA3[4];

        // -- P0: read F0(8) + F1(4); stage A half1; lgkm(4) -> F0 ready --
#pragma unroll
        for (int fm = 0; fm < 4; ++fm) fA0[fm] = *(const bf16x8*)(Ab + aoffb + fm * 1024);
#pragma unroll
        for (int ft = 0; ft < 4; ++ft) fB0[ft] = *(const bf16x8*)(Bbf + bo0 + ft * 1024);
#pragma unroll
        for (int fm = 0; fm < 4; ++fm) fA1[fm] = *(const bf16x8*)(Ab + aoffb + (fm + 4) * 1024);
        if (doA) { gload16(aW + aoffg + aslot[0], And + aslot[0]);
                   gload16(aW + aoffg + aslot[1], And + aslot[1]); }
        BAR; LGKM(4);
        __builtin_amdgcn_s_setprio(1);
#pragma unroll
        for (int fm = 0; fm < 4; ++fm)
#pragma unroll
            for (int ft = 0; ft < 4; ++ft)
                acc[fm][ft] = __builtin_amdgcn_mfma_f32_16x16x32_bf16(fA0[fm], fB0[ft], acc[fm][ft], 0, 0, 0);
        __builtin_amdgcn_s_setprio(0);
        BAR;

        // -- P1: read F2(8); stage A half2; lgkm(8) -> F1 ready --
#pragma unroll
        for (int fm = 0; fm < 4; ++fm) fA2[fm] = *(const bf16x8*)(Ab + 16384 + aoffb + fm * 1024);
#pragma unroll
        for (int ft = 0; ft < 4; ++ft) fB2[ft] = *(const bf16x8*)(Bbf + bo1 + ft * 1024);
        if (doA) { gload16(aW + aoffg + aslot[2], And + aslot[2]);
                   gload16(aW + aoffg + aslot[3], And + aslot[3]); }
        BAR; LGKM(8);
        __builtin_amdgcn_s_setprio(1);
#pragma unroll
        for (int fm = 0; fm < 4; ++fm)
#pragma unroll
            for (int ft = 0; ft < 4; ++ft)
                acc[fm + 4][ft] = __builtin_amdgcn_mfma_f32_16x16x32_bf16(fA1[fm], fB0[ft], acc[fm + 4][ft], 0, 0, 0);
        __builtin_amdgcn_s_setprio(0);
        BAR;

        // -- P2: read F3(4); stage B; lgkm(4) -> F2 ready --
#pragma unroll
        for (int fm = 0; fm < 4; ++fm) fA3[fm] = *(const bf16x8*)(Ab + 16384 + aoffb + (fm + 4) * 1024);
        if (doB) { gload16(bsrc[0] + badv, Bnd + bdst[0]);
                   gload16(bsrc[1] + badv, Bnd + bdst[1]); }
        BAR; LGKM(4);
        __builtin_amdgcn_s_setprio(1);
#pragma unroll
        for (int fm = 0; fm < 4; ++fm)
#pragma unroll
            for (int ft = 0; ft < 4; ++ft)
                acc[fm][ft] = __builtin_amdgcn_mfma_f32_16x16x32_bf16(fA2[fm], fB2[ft], acc[fm][ft], 0, 0, 0);
        __builtin_amdgcn_s_setprio(0);
        BAR;

        // -- P3: stage B tail; counted vmcnt; lgkm(0) -> F3 ready --
        if (doB) gload16(btsrc + badv, Bnd + 16384);
        if (s < 14) {
            if ((s & 1) == 0) asm volatile("s_waitcnt vmcnt(7)" ::: "memory");
            else              asm volatile("s_waitcnt vmcnt(4)" ::: "memory");
        } else if (s == 14)   asm volatile("s_waitcnt vmcnt(0)" ::: "memory");
        BAR; LGKM(0);
        __builtin_amdgcn_s_setprio(1);
#pragma unroll
        for (int fm = 0; fm < 4; ++fm)
#pragma unroll
            for (int ft = 0; ft < 4; ++ft)
                acc[fm + 4][ft] = __builtin_amdgcn_mfma_f32_16x16x32_bf16(fA3[fm], fB2[ft], acc[fm + 4][ft], 0, 0, 0);
        __builtin_amdgcn_s_setprio(0);
        BAR;
    }

    // ---- epilogue: D col=l15 -> t, row=lg*4+q -> h (r6-validated) ----
#pragma unroll
    for (int fm = 0; fm < 8; ++fm) {
        int hb = h0 + wr * 128 + fm * 16 + lg * 4;
        float4 bs = *(const float4*)&bias[hb];
        const float* bsp = (const float*)&bs;
#pragma unroll
        for (int q = 0; q < 4; ++q)
#pragma unroll
            for (int ft = 0; ft < 4; ++ft) {
                int t = t0 + wc * 64 + ft * 16 + l15;
                out[((size_t)(b * Hh + hb + q)) * Tt + t] = acc[fm][ft][q] + bsp[q];
            }
    }
}

// ---------------- fallback (ws too small): fp32 kernel ----------------
#define TT 256
#define HT 8
#define CT 4
__global__ __launch_bounds__(256) void conv1d_f32_kernel(
    const float* __restrict__ x, const float* __restrict__ W,
    const float* __restrict__ bias, float* __restrict__ out)
{
    const int tid = threadIdx.x;
    const int t0 = blockIdx.x * TT;
    const int h0 = blockIdx.y * HT;
    const int b  = blockIdx.z;
    __shared__ float xs[CT][TT + Kk];
    float acc[HT];
#pragma unroll
    for (int h = 0; h < HT; ++h) acc[h] = 0.f;
    const float* xb = x + (size_t)b * Cc * Tt;
    for (int c0 = 0; c0 < Cc; c0 += CT) {
        __syncthreads();
#pragma unroll
        for (int cc = 0; cc < CT; ++cc)
            for (int j = tid; j < TT + Kk - 1; j += 256) {
                int idx = t0 - (Kk - 1) + j;
                xs[cc][j] = (idx >= 0) ? xb[(size_t)(c0 + cc) * Tt + idx] : 0.f;
            }
        __syncthreads();
#pragma unroll
        for (int cc = 0; cc < CT; ++cc) {
            float xv[Kk];
#pragma unroll
            for (int k = 0; k < Kk; ++k) xv[k] = xs[cc][tid + k];
#pragma unroll
            for (int h = 0; h < HT; ++h) {
                const float* wp = W + (size_t)(h0 + h) * (Cc * Kk) + (size_t)(c0 + cc) * Kk;
#pragma unroll
                for (int k = 0; k < Kk; ++k) acc[h] += wp[k] * xv[k];
            }
        }
    }
#pragma unroll
    for (int h = 0; h < HT; ++h)
        out[((size_t)b * Hh + (h0 + h)) * Tt + t0 + tid] = acc[h] + bias[h0 + h];
}

extern "C" void kernel_launch(void* const* d_in, const int* in_sizes, int n_in,
                              void* d_out, int out_size, void* d_ws, size_t ws_size,
                              hipStream_t stream) {
    const float* x    = (const float*)d_in[0];
    const float* W    = (const float*)d_in[1];
    const float* bias = (const float*)d_in[2];
    float* out        = (float*)d_out;

    if (ws_size >= WS_NEEDED) {
        __hip_bfloat16* xT  = (__hip_bfloat16*)((char*)d_ws + WS_XT_OFF);
        __hip_bfloat16* Wt2 = (__hip_bfloat16*)((char*)d_ws + WS_WT_OFF);
        float* zeros        = (float*)((char*)d_ws + WS_ZERO_OFF);

        prep_kernel<<<dim3(4096), dim3(256), 0, stream>>>(x, W, xT, Wt2, zeros);
        conv_mfma_kernel<<<dim3(256), dim3(512), 0, stream>>>(xT, Wt2, bias, zeros, out);
    } else {
        conv1d_f32_kernel<<<dim3(Tt / TT, Hh / HT, Bb), dim3(256), 0, stream>>>(x, W, bias, out);
    }
}